// Round 8
// baseline (124.145 us; speedup 1.0000x reference)
//
#include <hip/hip_runtime.h>
#include <stdint.h>

#define NN 8192   // nodes
#define NE 8192   // edges
#define DIM 128
#define NL 17
#define SPLITK 8
#define KCHUNK (NN / SPLITK)   // 1024
#define NIT (KCHUNK / 32)      // 32

typedef float f32x4 __attribute__((ext_vector_type(4)));
typedef short short8 __attribute__((ext_vector_type(8)));

// ---- workspace layout (bytes) ----
#define WS_XHI    0ull                              // 2 MB  (xT blocked bf16)
#define WS_COLSUM (4ull << 20)                      // 64 KB (128 x 128 f32)
#define WS_C0E    ((4ull << 20) + (64ull << 10))    // 8.5 KB
#define WS_PART   (8ull << 20)                      // 32 MB (SPLITK x E x D f32)

// Round-to-nearest-even f32 -> bf16 bits.
__device__ __forceinline__ uint16_t f32_to_bf16(float v) {
  uint32_t u = __builtin_bit_cast(uint32_t, v);
  u += 0x7fffu + ((u >> 16) & 1u);
  return (uint16_t)(u >> 16);
}

// Prep: column sums of x (for x0), and x transposed into k-blocked bf16:
// xhi[kblk][d][kk] with kblk = k/32, kk = k%32. 128 blocks x 64 nodes.
__global__ __launch_bounds__(256) void k_prep(const float* __restrict__ x,
                                              uint16_t* __restrict__ xhi,
                                              float* __restrict__ colsum) {
  __shared__ float xs[64][129];
  const int t = threadIdx.x;
  const int b = blockIdx.x;  // nodes b*64 .. b*64+63
  const float4* xg = (const float4*)(x + (size_t)b * 64 * DIM);
  for (int r = 0; r < 8; ++r) {
    int f = t + r * 256;           // float4 index within tile
    float4 v = xg[f];
    int n = f >> 5;
    int d0 = (f & 31) * 4;
    xs[n][d0] = v.x; xs[n][d0 + 1] = v.y; xs[n][d0 + 2] = v.z; xs[n][d0 + 3] = v.w;
  }
  __syncthreads();
  if (t < 128) {
    float s = 0.f;
    for (int n = 0; n < 64; ++n) s += xs[n][t];
    colsum[b * DIM + t] = s;
  }
  // 1024 16B chunks: q = [kb(1)][d(7)][c(2)]
  for (int r = 0; r < 4; ++r) {
    int q = t + r * 256;
    int c = q & 3;
    int d = (q >> 2) & 127;
    int kb = q >> 9;
    int kk0 = c * 8;
    uint32_t w[4];
    for (int j = 0; j < 4; ++j) {
      uint16_t h0 = f32_to_bf16(xs[kb * 32 + kk0 + 2 * j][d]);
      uint16_t h1 = f32_to_bf16(xs[kb * 32 + kk0 + 2 * j + 1][d]);
      w[j] = (uint32_t)h0 | ((uint32_t)h1 << 16);
    }
    int kblk = b * 2 + kb;
    uint16_t* dst = xhi + ((size_t)(kblk * 128 + d)) * 32 + kk0;
    *(uint4*)dst = make_uint4(w[0], w[1], w[2], w[3]);
  }
}

// c0e[l][j] = x0 @ W[0,l] + B[l]; c0e[1] doubles as node-side constant.
__global__ __launch_bounds__(128) void k_c0e(const float* __restrict__ colsum,
                                             const float* __restrict__ W,
                                             const float* __restrict__ Bb,
                                             float* __restrict__ c0e) {
  __shared__ float x0[DIM];
  const int j = threadIdx.x;
  float s = 0.f;
  for (int b = 0; b < 128; ++b) s += colsum[b * DIM + j];
  x0[j] = s * (1.0f / NN);
  __syncthreads();
  const int l = blockIdx.x;
  const float* W0l = W + (size_t)l * DIM * DIM;
  float acc = Bb[l * DIM + j];
#pragma unroll 8
  for (int i = 0; i < DIM; ++i) acc += x0[i] * W0l[(size_t)i * DIM + j];
  c0e[l * DIM + j] = acc;
}

// Big MFMA GEMM: part[s][e][d] = sum_{k in chunk s} inc[k][e] * xhi[k][d].
// BARRIER-FREE: no LDS. B fragments load direct from global (coalesced 1KB
// per wave, identical across the 4 waves and across all 64 M-blocks at the
// same split -> L1/L2 broadcast). A/B double-buffered in registers; waves
// free-run, compiler schedules waitcnts. Bit-identical math to round 7.
__global__ __launch_bounds__(256, 2) void k_gemm(const float* __restrict__ inc,
                                                 const uint16_t* __restrict__ xhi,
                                                 float* __restrict__ part) {
  const int t = threadIdx.x;
  const int mb = blockIdx.x & 63;
  const int s = blockIdx.x >> 6;
  const int e0 = mb * 128;
  const int w = t >> 6;
  const int lane = t & 63;
  const int lm = lane & 15;
  const int lk = lane >> 4;          // 0..3
  const int kbase = s * KCHUNK;
  const int kb0 = kbase >> 5;        // first kblk

  f32x4 acc[2][8];
#pragma unroll
  for (int a = 0; a < 2; ++a)
#pragma unroll
    for (int b = 0; b < 8; ++b) acc[a][b] = (f32x4){0.f, 0.f, 0.f, 0.f};

#define LOADB(bv, kblk) { \
    const uint16_t* bp = xhi + (size_t)(kblk) * 4096; \
    _Pragma("unroll") \
    for (int fn = 0; fn < 8; ++fn) \
      bv[fn] = *(const short8*)(bp + (fn * 16 + lm) * 32 + lk * 8); \
  }

#define LOADA(u, it) { \
    const int k0_ = kbase + (it) * 32; \
    _Pragma("unroll") \
    for (int fm = 0; fm < 2; ++fm) { \
      const float* ap = inc + (size_t)(k0_ + lk * 8) * NE + (e0 + w * 32 + fm * 16 + lm); \
      _Pragma("unroll") \
      for (int j = 0; j < 8; ++j) \
        u[fm][j] = __builtin_bit_cast(uint32_t, ap[(size_t)j * NE]); \
    } }

#define COMPUTE(bv, u) { \
    short8 afr[2]; \
    _Pragma("unroll") \
    for (int fm = 0; fm < 2; ++fm) { \
      union { uint32_t w4[4]; short8 s8; } pk; \
      _Pragma("unroll") \
      for (int j = 0; j < 4; ++j) \
        pk.w4[j] = (u[fm][2 * j + 1] & 0xffff0000u) | (u[fm][2 * j] >> 16); \
      afr[fm] = pk.s8; \
    } \
    _Pragma("unroll") \
    for (int fn = 0; fn < 8; ++fn) { \
      acc[0][fn] = __builtin_amdgcn_mfma_f32_16x16x32_bf16(afr[0], bv[fn], acc[0][fn], 0, 0, 0); \
      acc[1][fn] = __builtin_amdgcn_mfma_f32_16x16x32_bf16(afr[1], bv[fn], acc[1][fn], 0, 0, 0); \
    } }

  short8 bA[8], bB[8];
  uint32_t uaA[2][8], uaB[2][8];
  LOADB(bA, kb0);
  LOADA(uaA, 0);

  for (int it2 = 0; it2 < NIT; it2 += 2) {
    if (it2 + 1 < NIT) { LOADB(bB, kb0 + it2 + 1); LOADA(uaB, it2 + 1); }
    COMPUTE(bA, uaA);
    if (it2 + 2 < NIT) { LOADB(bA, kb0 + it2 + 2); LOADA(uaA, it2 + 2); }
    COMPUTE(bB, uaB);
  }

  float* pbase = part + (size_t)s * NE * DIM;
#pragma unroll
  for (int fm = 0; fm < 2; ++fm)
#pragma unroll
    for (int fn = 0; fn < 8; ++fn)
#pragma unroll
      for (int r = 0; r < 4; ++r) {
        int e = e0 + w * 32 + fm * 16 + lk * 4 + r;
        int d = fn * 16 + lm;
        pbase[(size_t)e * DIM + d] = acc[fm][fn][r];
      }
#undef LOADB
#undef LOADA
#undef COMPUTE
}

// Per-edge: reduce split-K partials, normalize, matvec with W[1,order] + c0e.
__global__ __launch_bounds__(128) void k_edge2(const float* __restrict__ part,
                                               const int* __restrict__ orders,
                                               const float* __restrict__ norm,
                                               const float* __restrict__ W,
                                               const float* __restrict__ c0e,
                                               float* __restrict__ out_e) {
  __shared__ float xl[DIM];
  const int t = threadIdx.x;
  const int e = blockIdx.x;
  float s = 0.f;
#pragma unroll
  for (int k = 0; k < SPLITK; ++k)
    s += part[(size_t)k * NE * DIM + (size_t)e * DIM + t];
  xl[t] = s / norm[e];
  __syncthreads();
  const int l = orders[e];
  const float* W1l = W + (size_t)(NL + l) * DIM * DIM;
  float o = c0e[l * DIM + t];
#pragma unroll 8
  for (int i = 0; i < DIM; ++i) o += xl[i] * W1l[(size_t)i * DIM + t];
  out_e[(size_t)e * DIM + t] = o;
}

// Node side: out_v[n] = c0e[1] + x[n] @ W[1,1]. 4x4 register tile per thread.
__global__ __launch_bounds__(256) void k_node(const float* __restrict__ x,
                                              const float* __restrict__ W,
                                              const float* __restrict__ c0e,
                                              float* __restrict__ out_v) {
  __shared__ float xr[32][DIM];
  const int t = threadIdx.x;
  const int row0 = blockIdx.x * 32;
  for (int i = t; i < 32 * DIM; i += 256)
    xr[i >> 7][i & 127] = x[(size_t)row0 * DIM + i];
  const int tx = t & 31;
  const int ty = t >> 5;
  const float4* W4 = (const float4*)(W + (size_t)(NL + 1) * DIM * DIM);
  const float4 cv = ((const float4*)(c0e + DIM))[tx];
  float4 o0 = cv, o1 = cv, o2 = cv, o3 = cv;
  __syncthreads();
#pragma unroll 4
  for (int k = 0; k < DIM; ++k) {
    float4 w = W4[k * 32 + tx];
    float a0 = xr[ty * 4 + 0][k];
    float a1 = xr[ty * 4 + 1][k];
    float a2 = xr[ty * 4 + 2][k];
    float a3 = xr[ty * 4 + 3][k];
    o0.x += a0 * w.x; o0.y += a0 * w.y; o0.z += a0 * w.z; o0.w += a0 * w.w;
    o1.x += a1 * w.x; o1.y += a1 * w.y; o1.z += a1 * w.z; o1.w += a1 * w.w;
    o2.x += a2 * w.x; o2.y += a2 * w.y; o2.z += a2 * w.z; o2.w += a2 * w.w;
    o3.x += a3 * w.x; o3.y += a3 * w.y; o3.z += a3 * w.z; o3.w += a3 * w.w;
  }
  float4* out4 = (float4*)(out_v + (size_t)(row0 + ty * 4) * DIM);
  out4[0 * 32 + tx] = o0;
  out4[1 * 32 + tx] = o1;
  out4[2 * 32 + tx] = o2;
  out4[3 * 32 + tx] = o3;
}

extern "C" void kernel_launch(void* const* d_in, const int* in_sizes, int n_in,
                              void* d_out, int out_size, void* d_ws, size_t ws_size,
                              hipStream_t stream) {
  const float* x      = (const float*)d_in[0];
  const float* inc    = (const float*)d_in[1];
  const int*   orders = (const int*)d_in[2];
  const float* norm   = (const float*)d_in[3];
  const float* W      = (const float*)d_in[4];
  const float* Bb     = (const float*)d_in[5];
  float* out_v = (float*)d_out;
  float* out_e = (float*)d_out + (size_t)NN * DIM;

  char* ws = (char*)d_ws;
  uint16_t* xhi   = (uint16_t*)(ws + WS_XHI);
  float* colsum   = (float*)(ws + WS_COLSUM);
  float* c0e      = (float*)(ws + WS_C0E);
  float* part     = (float*)(ws + WS_PART);

  k_prep<<<128, 256, 0, stream>>>(x, xhi, colsum);
  k_c0e<<<NL, 128, 0, stream>>>(colsum, W, Bb, c0e);
  k_gemm<<<512, 256, 0, stream>>>(inc, xhi, part);
  k_edge2<<<NE, 128, 0, stream>>>(part, orders, norm, W, c0e, out_e);
  k_node<<<NN / 32, 256, 0, stream>>>(x, W, c0e, out_v);
}